// Round 20
// baseline (88.944 us; speedup 1.0000x reference)
//
#include <hip/hip_runtime.h>
#include <stdint.h>

// Problem constants (match reference)
#define B_N   8192
#define D_DIM 256
#define C_CLS 128
#define EPSV  1e-6f
#define DEPS  (256.0f * EPSV * EPSV)
#define D64EPS (64.0f * EPSV * EPSV)
#define NT    64                    // B_N / 128 tiles per dim
#define NTRI  (NT * (NT + 1) / 2)   // 2080 upper-tri tiles
#define PLANE (B_N * 16)            // 131072 B: one 16-B granule-plane

typedef float f32x4 __attribute__((ext_vector_type(4)));
typedef long long llx2 __attribute__((ext_vector_type(2)));

// Software fp32 -> fp8 e4m3fn (OCP), RNE, flush-subnormal, clamp to 448.
__device__ __forceinline__ unsigned f2fp8(float v) {
    unsigned u = __float_as_uint(v);
    unsigned s = (u >> 24) & 0x80;
    unsigned a = u & 0x7fffffff;
    if (a > 0x43E00000u) a = 0x43E00000u;
    a += 0x7FFFF + ((a >> 20) & 1);
    int e = (int)(a >> 23) - 120;
    if (e <= 0) return s;
    return s | ((unsigned)e << 3) | ((a >> 20) & 7);
}

// Workspace layout (bytes):
//   [0, 8192)          attrP[2048]
//   [8192, 16384)      ceP[2048]
//   [16384, 49664)     repP[8320]  (one per wave-tile, 4 per block)
//   [65536, +2MB)      e8: fp8 features in GRANULE-PLANE layout:
//     16 planes of [8192 rows x 16 B]. Plane p = 4*tp + q at row r holds
//     K-bytes {64tp+8q..+8} ++ {64tp+32+8q..+8}. Lane (q,l15) reads both
//     frags for chunks 2tp,2tp+1 as ONE dwordx4; a wave covers 4 dense
//     256-B runs -> uniform L2 channel hashing. tp-group 0 covers
//     ORIGINAL dims 0..63. K-perm is dot-product-invariant.
//   then aR[B], bC[B], aR64[B], bC64[B] fp32
//
// R31 = R27 resubmitted unchanged (broker timeouts R16-R19; audited twice:
// f32x4 epilogue loads are 16-B aligned (m0%64==0, mi*16, quad*4) and
// value-identical to the scalar form).
// R27 = R24 anchor (88.5us, R14 bench; passed, absmax 0.0) + f32x4
// epilogue loads. GRID-SYNC IS DEAD ON THIS TARGET, three ways tried:
//   R10: per-block __threadfence tail -> +23us (agent-scope fence = L2
//        writeback+inv per block on non-coherent-XCD gfx950; e8 evicted).
//   R12: fence-free atomic tail -> +10us (2080 contended same-address
//        cnt atomics serialize at the L2 atomic unit).
//   R15: hipLaunchCooperativeKernel NEVER EXECUTED (out[0]==0 -> absmax
//        = ref value 3.1875 exactly; uncaptured correctness phase, so
//        not a graph-capture artifact; likely co-residency rejection).
// The 3-kernel pipeline is final. SCREEN (R24): partial sum of squared
// diffs over dims 0..63 lower-bounds dist²; min >= 4.0 (fp8-safe: est
// <= 2.25 for any true-active pair) -> tile contributes exactly 0; only
// diagonal-crossing waves (~1.5%) run the full exact path.

// ---------------------------------------------------------------------------
// Kernel 1: fused row-stats + CE + fp8 cast (granule-plane store).
// Also emits 64-dim partial norms aR64/bC64 (2 extra masked butterfly terms).
__global__ __launch_bounds__(256) void k_prep(
        const float* __restrict__ feat, const float* __restrict__ cls,
        const int* __restrict__ labels, unsigned char* __restrict__ e8,
        float* __restrict__ aR, float* __restrict__ bC,
        float* __restrict__ aR64, float* __restrict__ bC64,
        float* __restrict__ attrP, float* __restrict__ ceP) {
    int t = threadIdx.x, lane = t & 63, w = t >> 6;
    int row = blockIdx.x * 4 + w;
    int lab = labels[row];

    const float4* src = (const float4*)(feat + (size_t)row * D_DIM);
    float4 f = src[lane];
    unsigned pk = f2fp8(f.x) | (f2fp8(f.y) << 8) | (f2fp8(f.z) << 16) | (f2fp8(f.w) << 24);
    // dword `lane` holds K-bytes 4*lane..+3 -> plane 4*(lane>>4)+((lane>>1)&3),
    // byte ((lane>>3)&1)*8 + (lane&1)*4.
    {
        int plane = ((lane >> 4) << 2) | ((lane >> 1) & 3);
        int off   = (((lane >> 3) & 1) << 3) | ((lane & 1) << 2);
        *(unsigned*)(e8 + (size_t)plane * PLANE + row * 16 + off) = pk;
    }

    float sq = f.x*f.x + f.y*f.y + f.z*f.z + f.w*f.w;
    float sm = f.x + f.y + f.z + f.w;
    float sq64 = (lane < 16) ? sq : 0.f;      // dims 0..63 = lanes 0..15
    float sm64 = (lane < 16) ? sm : 0.f;
    float arr[4] = {f.x, f.y, f.z, f.w};
    float pick = ((lab >> 2) == lane) ? arr[lab & 3] : 0.f;

    const float2* csrc = (const float2*)(cls + (size_t)row * C_CLS);
    float2 c2 = csrc[lane];
    float mx = fmaxf(c2.x, c2.y);
    #pragma unroll
    for (int off = 32; off; off >>= 1) mx = fmaxf(mx, __shfl_xor(mx, off));
    float es = expf(c2.x - mx) + expf(c2.y - mx);
    float cpick = ((lab >> 1) == lane) ? ((lab & 1) ? c2.y : c2.x) : 0.f;

    #pragma unroll
    for (int off = 32; off; off >>= 1) {
        sq    += __shfl_xor(sq, off);
        sm    += __shfl_xor(sm, off);
        sq64  += __shfl_xor(sq64, off);
        sm64  += __shfl_xor(sm64, off);
        pick  += __shfl_xor(pick, off);
        es    += __shfl_xor(es, off);
        cpick += __shfl_xor(cpick, off);
    }
    __shared__ float wsumA[4], wsumC[4];
    if (lane == 0) {
        aR[row]   = sq + 2.f * EPSV * sm;
        bC[row]   = sq - 2.f * EPSV * sm + DEPS;
        aR64[row] = sq64 + 2.f * EPSV * sm64;
        bC64[row] = sq64 - 2.f * EPSV * sm64 + D64EPS;
        float s = (lab & 1) ? -1.f : 1.f;
        wsumA[w] = sq - 2.f * s * pick + 1.f;     // sum_d (e-c)^2
        wsumC[w] = -(cpick - mx - logf(es));
    }
    __syncthreads();
    if (t == 0) {
        attrP[blockIdx.x] = wsumA[0] + wsumA[1] + wsumA[2] + wsumA[3];
        ceP[blockIdx.x]   = wsumC[0] + wsumC[1] + wsumC[2] + wsumC[3];
    }
}

// ---------------------------------------------------------------------------
// Kernel 2: LDS-free, barrier-free fp8 Gram + hinge, with tp0 screen.
// Each wave owns a 64x64 tile (4 waves = 128x128 upper-tri block tile).
// XCD-chunk-swizzle (T1, bijective: 2080%8==0). T5 setprio around MFMAs.
// Screen: 8 frag loads + 32 MFMAs + f32x4/scalar norm loads -> min
// partial; >= 4.0 (wave-uniform) -> rep=0, exit. Cold full path: tp=1..3
// serial (acc already holds tp0), exact epilogue identical to R22.
// No per-block atomics/fences. Per-wave repP write.
__global__ __launch_bounds__(256, 3) void k_gram(
        const unsigned char* __restrict__ e8, const float* __restrict__ aR,
        const float* __restrict__ bC, const float* __restrict__ aR64,
        const float* __restrict__ bC64, const int* __restrict__ labels,
        float* __restrict__ repP) {
    int t = threadIdx.x, lane = t & 63, w = t >> 6;

    // XCD-aware bijective swizzle: 8 contiguous chunks of 260 tiles.
    int swz = (blockIdx.x & 7) * (NTRI / 8) + (blockIdx.x >> 3);

    int bid = swz, tm = 0;
    while (bid >= NT - tm) { bid -= NT - tm; tm++; }
    int tn = tm + bid;

    int l15 = lane & 15, quad = lane >> 4;
    int wr = w >> 1, wc = w & 1;
    int m0 = tm * 128 + wr * 64, n0 = tn * 128 + wc * 64;

    // Row-part of the address within a plane (16 B per row).
    unsigned rowA[4], rowB[4];
    #pragma unroll
    for (int i = 0; i < 4; i++) {
        rowA[i] = (unsigned)(m0 + i * 16 + l15) * 16;
        rowB[i] = (unsigned)(n0 + i * 16 + l15) * 16;
    }

    f32x4 acc[4][4] = {};
    llx2 av[4], bv[4];

    // ---- screen phase: tp=0 (original dims 0..63) ----
    {
        const unsigned char* b0 = e8 + (size_t)quad * PLANE;
        #pragma unroll
        for (int mi = 0; mi < 4; mi++) av[mi] = *(const llx2*)(b0 + rowA[mi]);
        #pragma unroll
        for (int ni = 0; ni < 4; ni++) bv[ni] = *(const llx2*)(b0 + rowB[ni]);
    }
    f32x4 am64v[4];
    float bn64[4];
    #pragma unroll
    for (int mi = 0; mi < 4; mi++)
        am64v[mi] = *(const f32x4*)(aR64 + m0 + mi * 16 + quad * 4);
    #pragma unroll
    for (int ni = 0; ni < 4; ni++) bn64[ni] = bC64[n0 + ni * 16 + l15];

    __builtin_amdgcn_s_setprio(1);
    #pragma unroll
    for (int p = 0; p < 2; p++)
        #pragma unroll
        for (int mi = 0; mi < 4; mi++)
            #pragma unroll
            for (int ni = 0; ni < 4; ni++)
                acc[mi][ni] = __builtin_amdgcn_mfma_f32_16x16x32_fp8_fp8(
                    av[mi][p], bv[ni][p], acc[mi][ni], 0, 0, 0);
    __builtin_amdgcn_s_setprio(0);

    float minv = 1e30f;
    #pragma unroll
    for (int mi = 0; mi < 4; mi++)
        #pragma unroll
        for (int ni = 0; ni < 4; ni++)
            #pragma unroll
            for (int r = 0; r < 4; r++)
                minv = fminf(minv, fmaf(-2.f, acc[mi][ni][r], am64v[mi][r] + bn64[ni]));
    #pragma unroll
    for (int off = 32; off; off >>= 1) minv = fminf(minv, __shfl_xor(minv, off));

    if (minv >= 4.0f) {   // partial >= 4 -> full dist² >= 1 (fp8-safe) -> hinge 0
        if (lane == 0) repP[swz * 4 + w] = 0.f;
        return;
    }

    // ---- cold full path (~1.5% of waves: diagonal-crossing tiles) ----
    #pragma unroll
    for (int tp = 1; tp < 4; tp++) {
        const unsigned char* bp = e8 + (size_t)(4 * tp + quad) * PLANE;
        #pragma unroll
        for (int mi = 0; mi < 4; mi++) av[mi] = *(const llx2*)(bp + rowA[mi]);
        #pragma unroll
        for (int ni = 0; ni < 4; ni++) bv[ni] = *(const llx2*)(bp + rowB[ni]);
        __builtin_amdgcn_s_setprio(1);
        #pragma unroll
        for (int p = 0; p < 2; p++)
            #pragma unroll
            for (int mi = 0; mi < 4; mi++)
                #pragma unroll
                for (int ni = 0; ni < 4; ni++)
                    acc[mi][ni] = __builtin_amdgcn_mfma_f32_16x16x32_fp8_fp8(
                        av[mi][p], bv[ni][p], acc[mi][ni], 0, 0, 0);
        __builtin_amdgcn_s_setprio(0);
    }

    f32x4 amv[4];
    float bn[4];
    #pragma unroll
    for (int mi = 0; mi < 4; mi++)
        amv[mi] = *(const f32x4*)(aR + m0 + mi * 16 + quad * 4);
    #pragma unroll
    for (int ni = 0; ni < 4; ni++) bn[ni] = bC[n0 + ni * 16 + l15];

    float mfull = 1e30f;
    #pragma unroll
    for (int mi = 0; mi < 4; mi++)
        #pragma unroll
        for (int ni = 0; ni < 4; ni++)
            #pragma unroll
            for (int r = 0; r < 4; r++)
                mfull = fminf(mfull, fmaf(-2.f, acc[mi][ni][r], amv[mi][r] + bn[ni]));
    #pragma unroll
    for (int off = 32; off; off >>= 1) mfull = fminf(mfull, __shfl_xor(mfull, off));

    float rep = 0.f;
    if (mfull < 0.25f) {   // wave-uniform exact slow path
        int ln[4];
        #pragma unroll
        for (int ni = 0; ni < 4; ni++) ln[ni] = labels[n0 + ni * 16 + l15];
        #pragma unroll
        for (int mi = 0; mi < 4; mi++) {
            #pragma unroll
            for (int r = 0; r < 4; r++) {
                int m = m0 + mi * 16 + quad * 4 + r;   // C/D: row = quad*4+reg
                int lm = labels[m];
                #pragma unroll
                for (int ni = 0; ni < 4; ni++) {
                    int n = n0 + ni * 16 + l15;        // C/D: col = lane&15
                    float sq   = fmaf(-2.f, acc[mi][ni][r], amv[mi][r] + bn[ni]);
                    float dist = sqrtf(fmaxf(sq, 1e-12f));
                    float h    = fmaxf(0.5f - dist, 0.f);
                    rep += (lm != ln[ni] && m < n) ? h * h : 0.f;
                }
            }
        }
        #pragma unroll
        for (int off = 32; off; off >>= 1) rep += __shfl_xor(rep, off);
    }
    if (lane == 0) repP[swz * 4 + w] = rep;
}

// ---------------------------------------------------------------------------
// Kernel 3: sum partials, combine terms (float4 reads).
__global__ __launch_bounds__(256) void k_final(
        const float* __restrict__ P, float* __restrict__ out) {
    int t = threadIdx.x, lane = t & 63, w = t >> 6;
    const float4* P4 = (const float4*)P;
    float a = 0.f, c = 0.f, r = 0.f;
    for (int i = t; i < 512; i += 256) {
        float4 va = P4[i], vc = P4[512 + i];
        a += va.x + va.y + va.z + va.w;
        c += vc.x + vc.y + vc.z + vc.w;
    }
    for (int i = t; i < 2080; i += 256) {
        float4 vr = P4[1024 + i];
        r += vr.x + vr.y + vr.z + vr.w;
    }
    #pragma unroll
    for (int off = 32; off; off >>= 1) {
        a += __shfl_xor(a, off);
        c += __shfl_xor(c, off);
        r += __shfl_xor(r, off);
    }
    __shared__ float sa[4], sc[4], sr[4];
    if (lane == 0) { sa[w] = a; sc[w] = c; sr[w] = r; }
    __syncthreads();
    if (t == 0) {
        float attr = (sa[0] + sa[1] + sa[2] + sa[3]) / (float)((size_t)B_N * D_DIM);
        float ce   = (sc[0] + sc[1] + sc[2] + sc[3]) / (float)B_N;
        float rep  = (sr[0] + sr[1] + sr[2] + sr[3]) / ((float)B_N * (float)(B_N - 1) * 0.5f);
        out[0] = 0.5f * (attr + rep) + 0.5f * ce;   // BETA=0.5, ALPHA=0.5, W=1
    }
}

extern "C" void kernel_launch(void* const* d_in, const int* in_sizes, int n_in,
                              void* d_out, int out_size, void* d_ws, size_t ws_size,
                              hipStream_t stream) {
    const float* feat   = (const float*)d_in[0];
    const float* cls    = (const float*)d_in[1];
    const int*   labels = (const int*)d_in[2];
    float* out = (float*)d_out;

    float*          P    = (float*)d_ws;                       // partials
    unsigned char*  e8   = (unsigned char*)d_ws + 65536;
    float*          aR   = (float*)((char*)d_ws + 65536 + (size_t)B_N * D_DIM);
    float*          bC   = aR + B_N;
    float*          aR64 = bC + B_N;
    float*          bC64 = aR64 + B_N;

    k_prep <<<2048, 256, 0, stream>>>(feat, cls, labels, e8, aR, bC,
                                      aR64, bC64, P, P + 2048);
    k_gram <<<NTRI, 256, 0, stream>>>(e8, aR, bC, aR64, bC64, labels, P + 4096);
    k_final<<<1, 256, 0, stream>>>(P, out);
}